// Round 1
// baseline (461.274 us; speedup 1.0000x reference)
//
#include <hip/hip_runtime.h>
#include <hip/hip_bf16.h>
#include <stdint.h>
#include <stddef.h>

// ---------------------------------------------------------------------------
// NonLocalBlock2D: B=8, C=256, H=W=64 (N=4096), CI=128
// out = x + Wout * softmax( (theta(x)^T phi(x)) * sqrt(CI) ) * g(x)
// Precision strategy: split-fp32 (bf16 hi+lo, 3-MFMA) for everything feeding
// the softmax logits; plain bf16 MFMA after the softmax.
// ---------------------------------------------------------------------------

typedef __bf16 bf16;
typedef __attribute__((ext_vector_type(8))) __bf16 bf16x8;
typedef __attribute__((ext_vector_type(4))) __bf16 bf16x4;
typedef __attribute__((ext_vector_type(4))) float  f32x4;
typedef __attribute__((ext_vector_type(4))) int    i32x4;

#define MFMA16(a, b, c) __builtin_amdgcn_mfma_f32_16x16x32_bf16((a), (b), (c), 0, 0, 0)

constexpr int NB  = 8;
constexpr int NC  = 256;
constexpr int NN  = 4096;
constexpr int NCI = 128;
constexpr size_t NEL = (size_t)NB * NN * NCI;   // elements per [B,N,CI] array

// ---------------------------------------------------------------------------
// Kernel 1: projections.  out[n,i] = sum_c x[b,c,n] * W[i,c] + bias[i]
// pj=0 -> theta (split store qh/ql), pj=1 -> phi (split store kh/kl),
// pj=2 -> g (plain bf16 store v).
// Block: 256 thr (4 waves), tile [64 n x 128 i], K-chunks of 64 channels.
// ---------------------------------------------------------------------------
__global__ __launch_bounds__(256) void k_proj(
    const float* __restrict__ x,
    const float* __restrict__ wt, const float* __restrict__ bt,
    const float* __restrict__ wp, const float* __restrict__ bp,
    const float* __restrict__ wg, const float* __restrict__ bg,
    bf16* __restrict__ qh, bf16* __restrict__ ql,
    bf16* __restrict__ kh, bf16* __restrict__ kl,
    bf16* __restrict__ vv)
{
    const int nt  = blockIdx.x;      // 0..63  (n tile)
    const int pj  = blockIdx.y;      // 0..2   (projection)
    const int b   = blockIdx.z;      // 0..7
    const int tid = threadIdx.x;
    const int wv  = tid >> 6;
    const int ln  = tid & 63;

    const float* W;
    const float* bias;
    if (pj == 0)      { W = wt; bias = bt; }
    else if (pj == 1) { W = wp; bias = bp; }
    else              { W = wg; bias = bg; }
    const bool split = (pj != 2);

    __shared__ char lds[49152];
    char* Ah = lds;            // [64 n][64 c] bf16 (hi), swizzled, 8192 B
    char* Al = lds + 8192;     // lo
    char* Wh = lds + 16384;    // [128 i][64 c] bf16 (hi), swizzled, 16384 B
    char* Wl = lds + 32768;    // lo

    f32x4 acc[8];
#pragma unroll
    for (int j = 0; j < 8; ++j) acc[j] = f32x4{0.f, 0.f, 0.f, 0.f};

    const int n0 = nt * 64;

    for (int c0 = 0; c0 < NC; c0 += 64) {
        __syncthreads();
        // ---- stage A: x[b, c0+cc, n0+nn] -> Ah/Al[nn][cc] (transpose + split)
#pragma unroll
        for (int p = 0; p < 4; ++p) {
            int cc = p * 16 + (tid >> 4);
            int nn = (tid & 15) * 4;
            f32x4 xv = *(const f32x4*)(x + ((size_t)b * NC + (c0 + cc)) * NN + n0 + nn);
#pragma unroll
            for (int e = 0; e < 4; ++e) {
                float f = xv[e];
                bf16 h = (bf16)f;
                int row = nn + e;
                int off = (row * 128 + cc * 2) ^ ((row & 7) << 4);
                *(bf16*)(Ah + off) = h;
                *(bf16*)(Al + off) = (bf16)(f - (float)h);
            }
        }
        // ---- stage W: W[i, c0+c4..] -> Wh/Wl[i][c4..] (split)
#pragma unroll
        for (int p = 0; p < 8; ++p) {
            int i  = p * 16 + (tid >> 4);
            int c4 = (tid & 15) * 4;
            f32x4 w4 = *(const f32x4*)(W + (size_t)i * NC + c0 + c4);
            bf16x4 hv, lv;
#pragma unroll
            for (int e = 0; e < 4; ++e) {
                bf16 h = (bf16)w4[e];
                hv[e] = h;
                lv[e] = (bf16)(w4[e] - (float)h);
            }
            int off = (i * 128 + c4 * 2) ^ ((i & 7) << 4);
            *(bf16x4*)(Wh + off) = hv;
            if (split) *(bf16x4*)(Wl + off) = lv;
        }
        __syncthreads();
        // ---- MFMA: wave wv owns rows wv*16..wv*16+15, all 128 i
#pragma unroll
        for (int kk = 0; kk < 2; ++kk) {
            int row  = wv * 16 + (ln & 15);
            int koff = kk * 64 + (ln >> 4) * 16;     // byte offset in 128-B row
            int aoff = (row * 128 + koff) ^ ((row & 7) << 4);
            bf16x8 ah = *(const bf16x8*)(Ah + aoff);
            bf16x8 al = *(const bf16x8*)(Al + aoff);
#pragma unroll
            for (int j = 0; j < 8; ++j) {
                int ir   = j * 16 + (ln & 15);
                int woff = (ir * 128 + koff) ^ ((ir & 7) << 4);
                bf16x8 bh = *(const bf16x8*)(Wh + woff);
                acc[j] = MFMA16(ah, bh, acc[j]);
                if (split) {
                    bf16x8 bl = *(const bf16x8*)(Wl + woff);
                    acc[j] = MFMA16(ah, bl, acc[j]);
                    acc[j] = MFMA16(al, bh, acc[j]);
                }
            }
        }
    }

    // ---- epilogue: D layout col=lane&15 (i), row=(lane>>4)*4+r (n)
#pragma unroll
    for (int j = 0; j < 8; ++j) {
        int i = j * 16 + (ln & 15);
        float bv = bias[i];
#pragma unroll
        for (int r = 0; r < 4; ++r) {
            int q = n0 + wv * 16 + (ln >> 4) * 4 + r;
            size_t off = ((size_t)b * NN + q) * NCI + i;
            float val = acc[j][r] + bv;
            if (pj == 2) {
                vv[off] = (bf16)val;
            } else {
                bf16 h = (bf16)val;
                bf16 l = (bf16)(val - (float)h);
                if (pj == 0) { qh[off] = h; ql[off] = l; }
                else         { kh[off] = h; kl[off] = l; }
            }
        }
    }
}

// ---------------------------------------------------------------------------
// Kernel 2: flash attention.  256 blocks (b = bid&7 for XCD/L2 colocation),
// 512 thr = 8 waves, each wave owns 16 Q rows; K-tiles of 32, split QK^T
// (3 MFMAs), online softmax, PV via per-wave P buffer + transposed V in LDS.
// Writes y[b,n,i] (bf16) = softmax(S)*V  (y aliases qh: block reads its own
// Q rows first, writes the same rows at the very end).
// ---------------------------------------------------------------------------
__global__ __launch_bounds__(512) void k_attn(
    const bf16* __restrict__ qh, const bf16* __restrict__ ql,
    const bf16* __restrict__ kh, const bf16* __restrict__ kl,
    const bf16* __restrict__ v,  bf16* __restrict__ y)
{
    const int bid = blockIdx.x;       // 0..255
    const int b   = bid & 7;          // same batch -> same XCD (heuristic)
    const int qt  = bid >> 3;         // 0..31
    const int tid = threadIdx.x;
    const int wv  = tid >> 6;
    const int ln  = tid & 63;
    const int n0  = qt * 128;

    __shared__ char lds[32768];
    char* KH = lds;            // [32 m][128 d] bf16, swizzled (8 KB)
    char* KL = lds + 8192;
    char* VT = lds + 16384;    // [128 d][32 m] bf16, swizzled (8 KB)
    char* PB = lds + 24576;    // per-wave P [16 q][32 m] bf16 (1 KB each)
    char* P  = PB + wv * 1024;

    // ---- load Q fragments (hi/lo), rows n0 + wv*16 + (ln&15)
    bf16x8 qhf[4], qlf[4];
    {
        int qrow = n0 + wv * 16 + (ln & 15);
        const bf16* bh = qh + ((size_t)b * NN + qrow) * NCI;
        const bf16* bl = ql + ((size_t)b * NN + qrow) * NCI;
#pragma unroll
        for (int kk = 0; kk < 4; ++kk) {
            int d0 = kk * 32 + (ln >> 4) * 8;
            qhf[kk] = *(const bf16x8*)(bh + d0);
            qlf[kk] = *(const bf16x8*)(bl + d0);
        }
    }

    f32x4 o[8];
#pragma unroll
    for (int j = 0; j < 8; ++j) o[j] = f32x4{0.f, 0.f, 0.f, 0.f};
    float mrun[4], lrun[4];
#pragma unroll
    for (int r = 0; r < 4; ++r) { mrun[r] = -1e30f; lrun[r] = 0.f; }

    const float scale = 11.313708498984761f;  // sqrt(128)

    for (int m0 = 0; m0 < NN; m0 += 32) {
        __syncthreads();  // (A) all waves done with previous tile's LDS
        // ---- stage K (hi/lo) and transposed V
        {
            int mm = tid >> 4;            // 0..31
            int d0 = (tid & 15) * 8;      // 0..120
            size_t g = ((size_t)b * NN + m0 + mm) * NCI + d0;
            int off = (mm * 256 + d0 * 2) ^ ((mm & 7) << 4);
            *(i32x4*)(KH + off) = *(const i32x4*)(kh + g);
            *(i32x4*)(KL + off) = *(const i32x4*)(kl + g);
            bf16x8 v8 = *(const bf16x8*)(v + g);
#pragma unroll
            for (int e = 0; e < 8; ++e) {
                int d = d0 + e;
                int off2 = (d * 64 + mm * 2) ^ ((d & 7) << 4);
                *(bf16*)(VT + off2) = v8[e];
            }
        }
        __syncthreads();  // (B) staging visible

        // ---- QK^T (split, 3 MFMAs per chunk), S[q, m] scaled
        float pv[2][4];
#pragma unroll
        for (int jm = 0; jm < 2; ++jm) {
            f32x4 s = f32x4{0.f, 0.f, 0.f, 0.f};
            int mrow = jm * 16 + (ln & 15);
#pragma unroll
            for (int kk = 0; kk < 4; ++kk) {
                int koff = kk * 64 + (ln >> 4) * 16;
                int woff = (mrow * 256 + koff) ^ ((mrow & 7) << 4);
                bf16x8 bh = *(const bf16x8*)(KH + woff);
                bf16x8 bl = *(const bf16x8*)(KL + woff);
                s = MFMA16(qhf[kk], bh, s);
                s = MFMA16(qhf[kk], bl, s);
                s = MFMA16(qlf[kk], bh, s);
            }
#pragma unroll
            for (int r = 0; r < 4; ++r) pv[jm][r] = s[r] * scale;
        }

        // ---- online softmax (rows live in 16-lane groups)
        float tmax[4];
#pragma unroll
        for (int r = 0; r < 4; ++r) tmax[r] = fmaxf(pv[0][r], pv[1][r]);
#pragma unroll
        for (int d = 1; d < 16; d <<= 1)
#pragma unroll
            for (int r = 0; r < 4; ++r) tmax[r] = fmaxf(tmax[r], __shfl_xor(tmax[r], d));

        float alpha[4];
#pragma unroll
        for (int r = 0; r < 4; ++r) {
            float mnew = fmaxf(mrun[r], tmax[r]);
            alpha[r] = __expf(mrun[r] - mnew);
            mrun[r] = mnew;
        }
        float psum[4];
#pragma unroll
        for (int r = 0; r < 4; ++r) {
            pv[0][r] = __expf(pv[0][r] - mrun[r]);
            pv[1][r] = __expf(pv[1][r] - mrun[r]);
            psum[r] = pv[0][r] + pv[1][r];
        }
#pragma unroll
        for (int d = 1; d < 16; d <<= 1)
#pragma unroll
            for (int r = 0; r < 4; ++r) psum[r] += __shfl_xor(psum[r], d);
#pragma unroll
        for (int r = 0; r < 4; ++r) lrun[r] = lrun[r] * alpha[r] + psum[r];

        // ---- write P (bf16) to per-wave LDS; rescale O
#pragma unroll
        for (int jm = 0; jm < 2; ++jm)
#pragma unroll
            for (int r = 0; r < 4; ++r) {
                int q = (ln >> 4) * 4 + r;
                int m = jm * 16 + (ln & 15);
                int off = (q * 64 + m * 2) ^ (((q >> 1) & 3) << 4);
                *(bf16*)(P + off) = (bf16)pv[jm][r];
            }
#pragma unroll
        for (int j = 0; j < 8; ++j)
#pragma unroll
            for (int r = 0; r < 4; ++r) o[j][r] *= alpha[r];

        __syncthreads();  // (C) P visible (also orders P write -> read)

        // ---- PV: O[q, d] += P[q, m] * V[m, d]
        {
            int q = ln & 15;
            int koff = (ln >> 4) * 16;
            bf16x8 pa = *(const bf16x8*)(P + ((q * 64 + koff) ^ (((q >> 1) & 3) << 4)));
#pragma unroll
            for (int j = 0; j < 8; ++j) {
                int d = j * 16 + (ln & 15);
                bf16x8 bv = *(const bf16x8*)(VT + ((d * 64 + koff) ^ ((d & 7) << 4)));
                o[j] = MFMA16(pa, bv, o[j]);
            }
        }
    }

    // ---- epilogue: y = O / l
#pragma unroll
    for (int j = 0; j < 8; ++j) {
        int d = j * 16 + (ln & 15);
#pragma unroll
        for (int r = 0; r < 4; ++r) {
            int q = n0 + wv * 16 + (ln >> 4) * 4 + r;
            y[((size_t)b * NN + q) * NCI + d] = (bf16)(o[j][r] / lrun[r]);
        }
    }
}

// ---------------------------------------------------------------------------
// Kernel 3: out[b,c,n] = x[b,c,n] + sum_i y[b,n,i]*w_out[c,i] + b_out[c]
// Block: 256 thr (4 waves), tile [64 n x 256 c]; y staged in LDS, w_out
// converted fp32->bf16 inline (L2-resident, 128 KB).
// ---------------------------------------------------------------------------
__global__ __launch_bounds__(256) void k_out(
    const bf16* __restrict__ y, const float* __restrict__ x,
    const float* __restrict__ w_out, const float* __restrict__ b_out,
    float* __restrict__ out)
{
    const int nt  = blockIdx.x;   // 0..63
    const int b   = blockIdx.y;   // 0..7
    const int tid = threadIdx.x;
    const int wv  = tid >> 6;
    const int ln  = tid & 63;
    const int n0  = nt * 64;

    __shared__ char Y[16384];     // [64 n][128 i] bf16, swizzled
#pragma unroll
    for (int p = 0; p < 4; ++p) {
        int nn = p * 16 + (tid >> 4);
        int d0 = (tid & 15) * 8;
        i32x4 t = *(const i32x4*)(y + ((size_t)b * NN + n0 + nn) * NCI + d0);
        *(i32x4*)(Y + ((nn * 256 + d0 * 2) ^ ((nn & 7) << 4))) = t;
    }
    __syncthreads();

    bf16x8 af[4];
    {
        int row = wv * 16 + (ln & 15);
#pragma unroll
        for (int kk = 0; kk < 4; ++kk) {
            int koff = kk * 64 + (ln >> 4) * 16;
            af[kk] = *(const bf16x8*)(Y + ((row * 256 + koff) ^ ((row & 7) << 4)));
        }
    }

    f32x4 acc[16];
#pragma unroll
    for (int j = 0; j < 16; ++j) acc[j] = f32x4{0.f, 0.f, 0.f, 0.f};

#pragma unroll
    for (int j = 0; j < 16; ++j) {
        int c = j * 16 + (ln & 15);
#pragma unroll
        for (int kk = 0; kk < 4; ++kk) {
            int i0 = kk * 32 + (ln >> 4) * 8;
            f32x4 wa = *(const f32x4*)(w_out + (size_t)c * NCI + i0);
            f32x4 wb = *(const f32x4*)(w_out + (size_t)c * NCI + i0 + 4);
            bf16x8 bw;
#pragma unroll
            for (int e = 0; e < 4; ++e) { bw[e] = (bf16)wa[e]; bw[e + 4] = (bf16)wb[e]; }
            acc[j] = MFMA16(af[kk], bw, acc[j]);
        }
    }

#pragma unroll
    for (int j = 0; j < 16; ++j) {
        int c = j * 16 + (ln & 15);
        int nb = n0 + wv * 16 + (ln >> 4) * 4;
        size_t off = ((size_t)b * NC + c) * (size_t)NN + nb;
        f32x4 xv = *(const f32x4*)(x + off);
        float bo = b_out[c];
        f32x4 r;
#pragma unroll
        for (int t = 0; t < 4; ++t) r[t] = acc[j][t] + xv[t] + bo;
        *(f32x4*)(out + off) = r;
    }
}

// ---------------------------------------------------------------------------
extern "C" void kernel_launch(void* const* d_in, const int* in_sizes, int n_in,
                              void* d_out, int out_size, void* d_ws, size_t ws_size,
                              hipStream_t stream)
{
    (void)in_sizes; (void)n_in; (void)out_size; (void)ws_size;
    const float* x  = (const float*)d_in[0];
    const float* wg = (const float*)d_in[1];
    const float* bg = (const float*)d_in[2];
    const float* wt = (const float*)d_in[3];
    const float* bt = (const float*)d_in[4];
    const float* wp = (const float*)d_in[5];
    const float* bp = (const float*)d_in[6];
    const float* wo = (const float*)d_in[7];
    const float* bo = (const float*)d_in[8];
    float* out = (float*)d_out;

    char* ws = (char*)d_ws;
    bf16* qh = (bf16*)(ws);
    bf16* ql = (bf16*)(ws + NEL * 2);
    bf16* kh = (bf16*)(ws + NEL * 4);
    bf16* kl = (bf16*)(ws + NEL * 6);
    bf16* vv = (bf16*)(ws + NEL * 8);
    bf16* y  = qh;  // reuse: attn reads its own Q rows before writing same rows

    k_proj<<<dim3(64, 3, 8), 256, 0, stream>>>(x, wt, bt, wp, bp, wg, bg,
                                               qh, ql, kh, kl, vv);
    k_attn<<<dim3(256), 512, 0, stream>>>(qh, ql, kh, kl, vv, y);
    k_out<<<dim3(64, 8), 256, 0, stream>>>(y, x, wo, bo, out);
}

// Round 2
// 255.436 us; speedup vs baseline: 1.8058x; 1.8058x over previous
//
#include <hip/hip_runtime.h>
#include <hip/hip_bf16.h>
#include <stdint.h>
#include <stddef.h>

// ---------------------------------------------------------------------------
// NonLocalBlock2D: B=8, C=256, H=W=64 (N=4096), CI=128
// out = x + Wout * softmax( (theta(x)^T phi(x)) * sqrt(CI) ) * g(x)
// Split-fp32 (bf16 hi+lo, 3-MFMA) upstream of softmax; plain bf16 after.
// V stored transposed [b][ci][n] so attention stages it conflict-free.
// ---------------------------------------------------------------------------

typedef __bf16 bf16;
typedef __attribute__((ext_vector_type(8))) __bf16 bf16x8;
typedef __attribute__((ext_vector_type(4))) __bf16 bf16x4;
typedef __attribute__((ext_vector_type(4))) float  f32x4;
typedef __attribute__((ext_vector_type(4))) int    i32x4;

#define MFMA16(a, b, c) __builtin_amdgcn_mfma_f32_16x16x32_bf16((a), (b), (c), 0, 0, 0)

constexpr int NB  = 8;
constexpr int NC  = 256;
constexpr int NN  = 4096;
constexpr int NCI = 128;
constexpr size_t NEL = (size_t)NB * NN * NCI;

// ---------------------------------------------------------------------------
// Kernel 1: projections.  out[n,i] = sum_c x[b,c,n] * W[i,c] + bias[i]
// pj=0 -> theta (split qh/ql), pj=1 -> phi (split kh/kl),
// pj=2 -> g, stored TRANSPOSED: vv[b][i][n] (bf16) via LDS transpose.
// ---------------------------------------------------------------------------
__global__ __launch_bounds__(256) void k_proj(
    const float* __restrict__ x,
    const float* __restrict__ wt, const float* __restrict__ bt,
    const float* __restrict__ wp, const float* __restrict__ bp,
    const float* __restrict__ wg, const float* __restrict__ bg,
    bf16* __restrict__ qh, bf16* __restrict__ ql,
    bf16* __restrict__ kh, bf16* __restrict__ kl,
    bf16* __restrict__ vv)
{
    const int nt  = blockIdx.x;      // 0..63
    const int pj  = blockIdx.y;      // 0..2
    const int b   = blockIdx.z;      // 0..7
    const int tid = threadIdx.x;
    const int wv  = tid >> 6;
    const int ln  = tid & 63;
    const int lg  = ln >> 4;
    const int lq  = ln & 15;

    const float* W;
    const float* bias;
    if (pj == 0)      { W = wt; bias = bt; }
    else if (pj == 1) { W = wp; bias = bp; }
    else              { W = wg; bias = bg; }
    const bool split = (pj != 2);

    __shared__ char lds[49152];
    char* Ah = lds;            // [64 n][64 c] bf16 hi, swizzled
    char* Al = lds + 8192;
    char* Wh = lds + 16384;    // [128 i][64 c] bf16 hi, swizzled
    char* Wl = lds + 32768;

    f32x4 acc[8];
#pragma unroll
    for (int j = 0; j < 8; ++j) acc[j] = f32x4{0.f, 0.f, 0.f, 0.f};

    const int n0 = nt * 64;

    for (int c0 = 0; c0 < NC; c0 += 64) {
        __syncthreads();
        // stage A: x[b, c0+cc, n0+nn] -> Ah/Al[nn][cc] (transpose + split)
#pragma unroll
        for (int p = 0; p < 4; ++p) {
            int cc = p * 16 + (tid >> 4);
            int nn = (tid & 15) * 4;
            f32x4 xv = *(const f32x4*)(x + ((size_t)b * NC + (c0 + cc)) * NN + n0 + nn);
#pragma unroll
            for (int e = 0; e < 4; ++e) {
                float f = xv[e];
                bf16 h = (bf16)f;
                int row = nn + e;
                int off = (row * 128 + cc * 2) ^ ((row & 7) << 4);
                *(bf16*)(Ah + off) = h;
                *(bf16*)(Al + off) = (bf16)(f - (float)h);
            }
        }
        // stage W
#pragma unroll
        for (int p = 0; p < 8; ++p) {
            int i  = p * 16 + (tid >> 4);
            int c4 = (tid & 15) * 4;
            f32x4 w4 = *(const f32x4*)(W + (size_t)i * NC + c0 + c4);
            bf16x4 hv, lv;
#pragma unroll
            for (int e = 0; e < 4; ++e) {
                bf16 h = (bf16)w4[e];
                hv[e] = h;
                lv[e] = (bf16)(w4[e] - (float)h);
            }
            int off = (i * 128 + c4 * 2) ^ ((i & 7) << 4);
            *(bf16x4*)(Wh + off) = hv;
            if (split) *(bf16x4*)(Wl + off) = lv;
        }
        __syncthreads();
        // MFMA: wave wv owns n-rows wv*16..+15, all 128 i
#pragma unroll
        for (int kk = 0; kk < 2; ++kk) {
            int row  = wv * 16 + lq;
            int koff = kk * 64 + lg * 16;
            int aoff = (row * 128 + koff) ^ ((row & 7) << 4);
            bf16x8 ah = *(const bf16x8*)(Ah + aoff);
            bf16x8 al = *(const bf16x8*)(Al + aoff);
#pragma unroll
            for (int j = 0; j < 8; ++j) {
                int ir   = j * 16 + lq;
                int woff = (ir * 128 + koff) ^ ((ir & 7) << 4);
                bf16x8 bh = *(const bf16x8*)(Wh + woff);
                acc[j] = MFMA16(ah, bh, acc[j]);
                if (split) {
                    bf16x8 bl = *(const bf16x8*)(Wl + woff);
                    acc[j] = MFMA16(ah, bl, acc[j]);
                    acc[j] = MFMA16(al, bh, acc[j]);
                }
            }
        }
    }

    if (pj == 2) {
        // transpose epilogue: acc -> T[i][n_local] in LDS -> vv[b][i][n] coalesced
        __syncthreads();
        char* T = lds;   // [128 i][64 n] bf16, row 128B, swizzled
#pragma unroll
        for (int j = 0; j < 8; ++j) {
            int i = j * 16 + lq;
            float bv = bias[i];
#pragma unroll
            for (int r = 0; r < 4; ++r) {
                int nl = wv * 16 + lg * 4 + r;
                int off = (i * 128 + nl * 2) ^ ((i & 7) << 4);
                *(bf16*)(T + off) = (bf16)(acc[j][r] + bv);
            }
        }
        __syncthreads();
#pragma unroll
        for (int p = 0; p < 4; ++p) {
            int i  = p * 32 + (tid >> 3);
            int sl = tid & 7;
            i32x4 t = *(const i32x4*)(T + ((i * 128 + sl * 16) ^ ((i & 7) << 4)));
            *(i32x4*)(vv + ((size_t)b * NCI + i) * NN + n0 + sl * 8) = t;
        }
    } else {
#pragma unroll
        for (int j = 0; j < 8; ++j) {
            int i = j * 16 + lq;
            float bv = bias[i];
#pragma unroll
            for (int r = 0; r < 4; ++r) {
                int q = n0 + wv * 16 + lg * 4 + r;
                size_t off = ((size_t)b * NN + q) * NCI + i;
                float val = acc[j][r] + bv;
                bf16 h = (bf16)val;
                bf16 l = (bf16)(val - (float)h);
                if (pj == 0) { qh[off] = h; ql[off] = l; }
                else         { kh[off] = h; kl[off] = l; }
            }
        }
    }
}

// ---------------------------------------------------------------------------
// Kernel 2: flash attention, swapped QK^T (S^T = K*Q), BK=64, 2 barriers/iter.
// 512 blocks x 256 thr (2 blocks/CU, same batch per CU pair), 4 waves x 16 q.
// ---------------------------------------------------------------------------
__global__ __launch_bounds__(256, 2) void k_attn(
    const bf16* __restrict__ qh, const bf16* __restrict__ ql,
    const bf16* __restrict__ kh, const bf16* __restrict__ kl,
    const bf16* __restrict__ vt, bf16* __restrict__ y)
{
    const int bid = blockIdx.x;       // 0..511
    const int b   = bid & 7;
    const int qt  = bid >> 3;         // 0..63
    const int tid = threadIdx.x;
    const int wv  = tid >> 6;
    const int ln  = tid & 63;
    const int lg  = ln >> 4;          // 0..3
    const int lq  = ln & 15;
    const int n0  = qt * 64;

    __shared__ char lds[57344];
    char* KH = lds;                   // [64 m][128 d] bf16, row 256B, swizzled
    char* KL = lds + 16384;
    char* VT = lds + 32768;           // [128 d][64 m] bf16, row 128B, swizzled
    char* P  = lds + 49152 + wv * 2048; // per-wave [16 q][64 m] bf16, swizzled

    // Q fragments (loop-invariant, registers). B-frag: col=lq=q, k=lg*8+e.
    bf16x8 qhf[4], qlf[4];
    {
        int qrow = n0 + wv * 16 + lq;
        const bf16* bh = qh + ((size_t)b * NN + qrow) * NCI;
        const bf16* bl = ql + ((size_t)b * NN + qrow) * NCI;
#pragma unroll
        for (int kk = 0; kk < 4; ++kk) {
            int d0 = kk * 32 + lg * 8;
            qhf[kk] = *(const bf16x8*)(bh + d0);
            qlf[kk] = *(const bf16x8*)(bl + d0);
        }
    }

    f32x4 o[8];
#pragma unroll
    for (int j = 0; j < 8; ++j) o[j] = f32x4{0.f, 0.f, 0.f, 0.f};
    float mrun = -1e30f, lrun = 0.f;
    const float scale = 11.313708498984761f;   // sqrt(128)

    for (int m0 = 0; m0 < NN; m0 += 64) {
        __syncthreads();   // (A) previous tile fully consumed
        // ---- stage K hi/lo: [m][d], vectorized, uniform banks
#pragma unroll
        for (int p = 0; p < 4; ++p) {
            int mm = p * 16 + (tid >> 4);
            int sl = tid & 15;
            size_t g = ((size_t)b * NN + m0 + mm) * NCI + sl * 8;
            int off = (mm * 256 + sl * 16) ^ ((mm & 7) << 4);
            *(i32x4*)(KH + off) = *(const i32x4*)(kh + g);
            *(i32x4*)(KL + off) = *(const i32x4*)(kl + g);
        }
        // ---- stage V^T: [d][m], vectorized from pre-transposed global
#pragma unroll
        for (int p = 0; p < 4; ++p) {
            int d  = p * 32 + (tid >> 3);
            int sl = tid & 7;
            size_t g = ((size_t)b * NCI + d) * NN + m0 + sl * 8;
            int off = (d * 128 + sl * 16) ^ ((d & 7) << 4);
            *(i32x4*)(VT + off) = *(const i32x4*)(vt + g);
        }
        __syncthreads();   // (B) staging visible

        // ---- swapped QK^T: S^T[m][q] tiles, A=K (LDS), B=Q (regs)
        float pv[4][4];
        __builtin_amdgcn_s_setprio(1);
#pragma unroll
        for (int jm = 0; jm < 4; ++jm) {
            f32x4 s = f32x4{0.f, 0.f, 0.f, 0.f};
            int mrow = jm * 16 + lq;
#pragma unroll
            for (int kk = 0; kk < 4; ++kk) {
                int aoff = (mrow * 256 + kk * 64 + lg * 16) ^ ((mrow & 7) << 4);
                bf16x8 ah = *(const bf16x8*)(KH + aoff);
                bf16x8 al = *(const bf16x8*)(KL + aoff);
                s = MFMA16(ah, qhf[kk], s);
                s = MFMA16(al, qhf[kk], s);
                s = MFMA16(ah, qlf[kk], s);
            }
#pragma unroll
            for (int r = 0; r < 4; ++r) pv[jm][r] = s[r] * scale;
        }
        __builtin_amdgcn_s_setprio(0);

        // ---- online softmax. Lane owns column q=lq; 16 values m=jm*16+lg*4+r.
        float tmax = pv[0][0];
#pragma unroll
        for (int jm = 0; jm < 4; ++jm)
#pragma unroll
            for (int r = 0; r < 4; ++r) tmax = fmaxf(tmax, pv[jm][r]);
        tmax = fmaxf(tmax, __shfl_xor(tmax, 16));
        tmax = fmaxf(tmax, __shfl_xor(tmax, 32));
        float mnew = fmaxf(mrun, tmax);
        float alpha = __expf(mrun - mnew);
        mrun = mnew;
        float psum = 0.f;
#pragma unroll
        for (int jm = 0; jm < 4; ++jm)
#pragma unroll
            for (int r = 0; r < 4; ++r) {
                pv[jm][r] = __expf(pv[jm][r] - mnew);
                psum += pv[jm][r];
            }
        psum += __shfl_xor(psum, 16);
        psum += __shfl_xor(psum, 32);
        lrun = lrun * alpha + psum;

        // ---- write P packed (4 consecutive m per reg group -> b64 writes)
#pragma unroll
        for (int jm = 0; jm < 4; ++jm) {
            bf16x4 pk;
#pragma unroll
            for (int r = 0; r < 4; ++r) pk[r] = (bf16)pv[jm][r];
            int off = (lq * 128 + (jm * 16 + lg * 4) * 2) ^ ((lq & 7) << 4);
            *(bf16x4*)(P + off) = pk;
        }

        // ---- rescale O (alpha for q=lg*4+r lives in lane lg*4+r)
        float av[4];
#pragma unroll
        for (int r = 0; r < 4; ++r) av[r] = __shfl(alpha, lg * 4 + r);
#pragma unroll
        for (int j = 0; j < 8; ++j)
#pragma unroll
            for (int r = 0; r < 4; ++r) o[j][r] *= av[r];

        // ---- PV: O[q][d] += P[q][m] * V[m][d]; A=P, B=V^T rows
        bf16x8 pa[2];
#pragma unroll
        for (int t = 0; t < 2; ++t)
            pa[t] = *(const bf16x8*)(P + ((lq * 128 + t * 64 + lg * 16) ^ ((lq & 7) << 4)));
        __builtin_amdgcn_s_setprio(1);
#pragma unroll
        for (int j = 0; j < 8; ++j) {
            int d = j * 16 + lq;
#pragma unroll
            for (int t = 0; t < 2; ++t) {
                bf16x8 bv = *(const bf16x8*)(VT + ((d * 128 + t * 64 + lg * 16) ^ ((d & 7) << 4)));
                o[j] = MFMA16(pa[t], bv, o[j]);
            }
        }
        __builtin_amdgcn_s_setprio(0);
    }

    // ---- epilogue: y = O / l
    float lr[4];
#pragma unroll
    for (int r = 0; r < 4; ++r) lr[r] = __shfl(lrun, lg * 4 + r);
#pragma unroll
    for (int j = 0; j < 8; ++j) {
        int d = j * 16 + lq;
#pragma unroll
        for (int r = 0; r < 4; ++r) {
            int q = n0 + wv * 16 + lg * 4 + r;
            y[((size_t)b * NN + q) * NCI + d] = (bf16)(o[j][r] / lr[r]);
        }
    }
}

// ---------------------------------------------------------------------------
// Kernel 3: out[b,c,n] = x[b,c,n] + sum_i y[b,n,i]*w_out[c,i] + b_out[c]
// ---------------------------------------------------------------------------
__global__ __launch_bounds__(256) void k_out(
    const bf16* __restrict__ y, const float* __restrict__ x,
    const float* __restrict__ w_out, const float* __restrict__ b_out,
    float* __restrict__ out)
{
    const int nt  = blockIdx.x;
    const int b   = blockIdx.y;
    const int tid = threadIdx.x;
    const int wv  = tid >> 6;
    const int ln  = tid & 63;
    const int lg  = ln >> 4;
    const int lq  = ln & 15;
    const int n0  = nt * 64;

    __shared__ char Y[16384];   // [64 n][128 i] bf16, swizzled
#pragma unroll
    for (int p = 0; p < 4; ++p) {
        int nn = p * 16 + (tid >> 4);
        int d0 = (tid & 15) * 8;
        i32x4 t = *(const i32x4*)(y + ((size_t)b * NN + n0 + nn) * NCI + d0);
        *(i32x4*)(Y + ((nn * 256 + d0 * 2) ^ ((nn & 7) << 4))) = t;
    }
    __syncthreads();

    bf16x8 af[4];
    {
        int row = wv * 16 + lq;
#pragma unroll
        for (int kk = 0; kk < 4; ++kk) {
            int koff = kk * 64 + lg * 16;
            af[kk] = *(const bf16x8*)(Y + ((row * 256 + koff) ^ ((row & 7) << 4)));
        }
    }

    f32x4 acc[16];
#pragma unroll
    for (int j = 0; j < 16; ++j) acc[j] = f32x4{0.f, 0.f, 0.f, 0.f};

#pragma unroll
    for (int j = 0; j < 16; ++j) {
        int c = j * 16 + lq;
#pragma unroll
        for (int kk = 0; kk < 4; ++kk) {
            int i0 = kk * 32 + lg * 8;
            f32x4 wa = *(const f32x4*)(w_out + (size_t)c * NCI + i0);
            f32x4 wb = *(const f32x4*)(w_out + (size_t)c * NCI + i0 + 4);
            bf16x8 bw;
#pragma unroll
            for (int e = 0; e < 4; ++e) { bw[e] = (bf16)wa[e]; bw[e + 4] = (bf16)wb[e]; }
            acc[j] = MFMA16(af[kk], bw, acc[j]);
        }
    }

#pragma unroll
    for (int j = 0; j < 16; ++j) {
        int c = j * 16 + lq;
        int nb = n0 + wv * 16 + lg * 4;
        size_t off = ((size_t)b * NC + c) * (size_t)NN + nb;
        f32x4 xv = *(const f32x4*)(x + off);
        float bo = b_out[c];
        f32x4 r;
#pragma unroll
        for (int t = 0; t < 4; ++t) r[t] = acc[j][t] + xv[t] + bo;
        *(f32x4*)(out + off) = r;
    }
}

// ---------------------------------------------------------------------------
extern "C" void kernel_launch(void* const* d_in, const int* in_sizes, int n_in,
                              void* d_out, int out_size, void* d_ws, size_t ws_size,
                              hipStream_t stream)
{
    (void)in_sizes; (void)n_in; (void)out_size; (void)ws_size;
    const float* x  = (const float*)d_in[0];
    const float* wg = (const float*)d_in[1];
    const float* bg = (const float*)d_in[2];
    const float* wt = (const float*)d_in[3];
    const float* bt = (const float*)d_in[4];
    const float* wp = (const float*)d_in[5];
    const float* bp = (const float*)d_in[6];
    const float* wo = (const float*)d_in[7];
    const float* bo = (const float*)d_in[8];
    float* out = (float*)d_out;

    char* ws = (char*)d_ws;
    bf16* qh = (bf16*)(ws);
    bf16* ql = (bf16*)(ws + NEL * 2);
    bf16* kh = (bf16*)(ws + NEL * 4);
    bf16* kl = (bf16*)(ws + NEL * 6);
    bf16* vv = (bf16*)(ws + NEL * 8);   // transposed: [b][ci][n]
    bf16* y  = qh;  // reuse: attn block reads its own Q rows before writing them

    k_proj<<<dim3(64, 3, 8), 256, 0, stream>>>(x, wt, bt, wp, bp, wg, bg,
                                               qh, ql, kh, kl, vv);
    k_attn<<<dim3(512), 256, 0, stream>>>(qh, ql, kh, kl, vv, y);
    k_out<<<dim3(64, 8), 256, 0, stream>>>(y, x, wo, bo, out);
}